// Round 13
// baseline (923.511 us; speedup 1.0000x reference)
//
#include <hip/hip_runtime.h>
#include <cstdint>
#include <cstddef>

#define EPSV 1e-5f
#define CAP 224      // candidate list capacity per row (>= K+PAD for K<=192)
#define PAD 16       // extra candidates beyond k
#define DELTA 0.03f  // ambiguity half-window >= 2*E_max(approx err ~8e-3); 0.012 FAILED R7, 0.02/0.03 passed
#define AMBCAP 64

// ---------- bf16 helpers (bit-level, RNE) ----------
__device__ __forceinline__ unsigned short f2bf(float f) {
  unsigned u = __float_as_uint(f);
  unsigned r = (u + 0x7FFFu + ((u >> 16) & 1u)) >> 16;
  return (unsigned short)r;
}
__device__ __forceinline__ float bf2f(unsigned short h) {
  return __uint_as_float(((unsigned)h) << 16);
}

// ---------------- LayerNorm: a = (x-mean)/(std+eps) - pre_bias; also emit bf16 hi panel ----------------
__global__ __launch_bounds__(256) void ln_kernel(const float* __restrict__ x,
    const float* __restrict__ pre_bias, float* __restrict__ a,
    unsigned short* __restrict__ A2,   // [B][2048] bf16 (may be null)
    float* __restrict__ stats, int D) {
  const int b = blockIdx.x;
  const int tid = threadIdx.x;
  const float4* x4 = reinterpret_cast<const float4*>(x + (size_t)b * D);
  const float4* pb4 = reinterpret_cast<const float4*>(pre_bias);
  float4* a4 = reinterpret_cast<float4*>(a + (size_t)b * D);
  float4 v0 = x4[tid], v1 = x4[tid + 256];
  float s = v0.x + v0.y + v0.z + v0.w + v1.x + v1.y + v1.z + v1.w;
  float ss = v0.x*v0.x + v0.y*v0.y + v0.z*v0.z + v0.w*v0.w
           + v1.x*v1.x + v1.y*v1.y + v1.z*v1.z + v1.w*v1.w;
#pragma unroll
  for (int off = 1; off < 64; off <<= 1) { s += __shfl_xor(s, off); ss += __shfl_xor(ss, off); }
  __shared__ float wsum[4], wssq[4], bmean, bstd;
  int wave = tid >> 6;
  if ((tid & 63) == 0) { wsum[wave] = s; wssq[wave] = ss; }
  __syncthreads();
  if (tid == 0) {
    float S1 = wsum[0] + wsum[1] + wsum[2] + wsum[3];
    float S2 = wssq[0] + wssq[1] + wssq[2] + wssq[3];
    float mean = S1 / (float)D;
    float var = (S2 - (float)D * mean * mean) / (float)(D - 1);
    float sd = sqrtf(fmaxf(var, 0.f));
    bmean = mean; bstd = sd;
    stats[2*b] = mean; stats[2*b+1] = sd;
  }
  __syncthreads();
  float mean = bmean, rstd = 1.f / (bstd + EPSV);
  float4 p0 = pb4[tid], p1 = pb4[tid + 256];
  float4 o0, o1;
  o0.x = (v0.x - mean) * rstd - p0.x; o0.y = (v0.y - mean) * rstd - p0.y;
  o0.z = (v0.z - mean) * rstd - p0.z; o0.w = (v0.w - mean) * rstd - p0.w;
  o1.x = (v1.x - mean) * rstd - p1.x; o1.y = (v1.y - mean) * rstd - p1.y;
  o1.z = (v1.z - mean) * rstd - p1.z; o1.w = (v1.w - mean) * rstd - p1.w;
  a4[tid] = o0; a4[tid + 256] = o1;
  if (A2) {
    unsigned short* row = A2 + (size_t)b * 2048;
    ushort4 h0 = make_ushort4(f2bf(o0.x), f2bf(o0.y), f2bf(o0.z), f2bf(o0.w));
    ushort4 h1 = make_ushort4(f2bf(o1.x), f2bf(o1.y), f2bf(o1.z), f2bf(o1.w));
    *reinterpret_cast<ushort4*>(row + tid * 4) = h0;
    *reinterpret_cast<ushort4*>(row + 1024 + tid * 4) = h1;
  }
}

// ---------------- A2 [B][2048] -> A2F fragmentized: A2F[mt][kc][lane][8] ----------------
// MFMA A-operand (16x16x32): lane l holds row (l&15), cols (l>>4)*8..+8 of the
// 16-row x 32-col fragment. Storing each fragment's 64 lanes contiguously (1KB)
// makes the GEMM's A-fragment load a perfectly coalesced global_load_dwordx4.
__global__ __launch_bounds__(256) void repack_a(const unsigned short* __restrict__ A2,
    unsigned short* __restrict__ A2F) {
  const int mt = blockIdx.x;           // 16-row tile index
  const int tid = threadIdx.x;
  for (int idx = tid; idx < 64 * 64; idx += 256) {   // kc (64) x lane (64)
    int kc = idx >> 6, l = idx & 63;
    const unsigned short* src = A2 + (size_t)(mt * 16 + (l & 15)) * 2048 + kc * 32 + (l >> 4) * 8;
    unsigned short* dst = A2F + ((size_t)mt * 64 + kc) * 512 + (size_t)l * 8;
    *reinterpret_cast<uint4*>(dst) = *reinterpret_cast<const uint4*>(src);
  }
}

// ---------------- W_enc [S][2048] f32 -> W2 [S][2048] bf16 ----------------
__global__ __launch_bounds__(256) void cvt_w_kernel(const float* __restrict__ W,
    unsigned short* __restrict__ W2, int D) {
  const int s = blockIdx.x, tid = threadIdx.x;
  const float4* w4 = reinterpret_cast<const float4*>(W + (size_t)s * D);
  unsigned short* row = W2 + (size_t)s * D;
  float4 v0 = w4[tid * 2], v1 = w4[tid * 2 + 1];
  uint4 p;
  p.x = (unsigned)f2bf(v0.x) | ((unsigned)f2bf(v0.y) << 16);
  p.y = (unsigned)f2bf(v0.z) | ((unsigned)f2bf(v0.w) << 16);
  p.z = (unsigned)f2bf(v1.x) | ((unsigned)f2bf(v1.y) << 16);
  p.w = (unsigned)f2bf(v1.z) | ((unsigned)f2bf(v1.w) << 16);
  *reinterpret_cast<uint4*>(row + tid * 8) = p;
}

// ---------------- bf16 MFMA encode GEMM: C = A·W^T + sae_bias, K=2048 ----------------
typedef __attribute__((ext_vector_type(8))) short bf8;
typedef __attribute__((ext_vector_type(4))) float f32x4;

__device__ __forceinline__ void gload16(const void* g, void* l) {
  __builtin_amdgcn_global_load_lds(
      (const __attribute__((address_space(1))) unsigned int*)g,
      (__attribute__((address_space(3))) unsigned int*)l,
      16, 0, 0);
}

// R13: A comes REGISTER-DIRECT from the fragmentized A2F layout (coalesced
// 1KB-per-wave loads) — eliminates A's LDS writes AND its 2/3 share of
// fragment ds_reads (LDS was 86% busy = the binding resource). Only B is
// LDS-staged (16KB x 2 dbuf = 32KB). Same proven 2-phase schedule
// (STAGE-next-before-COMPUTE-cur, vmcnt(0)+raw barrier), T2 swizzle on B,
// T5 setprio. 512 threads / 8 waves (2M x 4N), wave tile 64x32.
__global__ __launch_bounds__(512) void enc_gemm_bf16(
    const unsigned short* __restrict__ A2F,  // fragmentized [B/16][64][64][8]
    const unsigned short* __restrict__ W2,   // [N][2048]
    const float* __restrict__ sae_bias,
    float* __restrict__ C, int M, int N) {
  __shared__ __align__(16) short Bs0[128 * 64];
  __shared__ __align__(16) short Bs1[128 * 64];
  const int tid = threadIdx.x;
  const int bn = blockIdx.x, bm = blockIdx.y;
  const int w = tid >> 6, l = tid & 63;

  // B staging: 1024 16B-slots per K-tile; 2 rounds of 512 threads
  const unsigned short* gB[2];
  int ldsSlot[2];
#pragma unroll
  for (int r = 0; r < 2; ++r) {
    int slot = r * 512 + tid;
    int row = slot >> 3, unit = slot & 7;
    int gcol = (unit ^ (row & 7)) * 8;      // pre-swizzled global 16B unit
    gB[r] = W2 + (size_t)(bn * 128 + row) * 2048 + gcol;
    ldsSlot[r] = slot * 8;                  // linear LDS dest (elems)
  }

  // wave tile: 64(M) x 32(N)
  const int wm = (w >> 2) * 64, wn = (w & 3) * 32;
  const int r15 = l & 15, b7 = l & 7, u = l >> 4;
  const int colks0 = ((u + 0) ^ b7) * 8;    // ks=0 physical col offset (elems)
  const int colks1 = ((u + 4) ^ b7) * 8;    // ks=1
  const int baseB = (wn + r15) * 64;

  // A fragment base: wave's first m-tile = bm*8 + wm/16; lane offset l*8
  const unsigned short* gAF = A2F + ((size_t)(bm * 8 + (wm >> 4)) * 64) * 512 + (size_t)l * 8;

  f32x4 acc[4][2];
#pragma unroll
  for (int mi = 0; mi < 4; ++mi)
#pragma unroll
    for (int ni = 0; ni < 2; ++ni) acc[mi][ni] = (f32x4){0.f, 0.f, 0.f, 0.f};

#define STAGEB(Bdst, koff)                                        \
  {                                                               \
    _Pragma("unroll")                                             \
    for (int r = 0; r < 2; ++r)                                   \
      gload16(gB[r] + (koff), &(Bdst)[ldsSlot[r]]);               \
  }

#define COMPUTE(Bsrc, t)                                          \
  {                                                               \
    bf8 af[8], bfv[4];                                            \
    _Pragma("unroll")                                             \
    for (int mi = 0; mi < 4; ++mi) {                              \
      af[mi]     = *reinterpret_cast<const bf8*>(gAF + ((size_t)mi * 64 + 2 * (t)) * 512);     \
      af[4 + mi] = *reinterpret_cast<const bf8*>(gAF + ((size_t)mi * 64 + 2 * (t) + 1) * 512); \
    }                                                             \
    _Pragma("unroll")                                             \
    for (int ni = 0; ni < 2; ++ni) {                              \
      bfv[ni]     = *reinterpret_cast<const bf8*>(&(Bsrc)[baseB + ni * 1024 + colks0]); \
      bfv[2 + ni] = *reinterpret_cast<const bf8*>(&(Bsrc)[baseB + ni * 1024 + colks1]); \
    }                                                             \
    __builtin_amdgcn_s_setprio(1);                                \
    _Pragma("unroll")                                             \
    for (int mi = 0; mi < 4; ++mi)                                \
      _Pragma("unroll")                                           \
      for (int ni = 0; ni < 2; ++ni)                              \
        acc[mi][ni] = __builtin_amdgcn_mfma_f32_16x16x32_bf16(    \
            af[mi], bfv[ni], acc[mi][ni], 0, 0, 0);               \
    _Pragma("unroll")                                             \
    for (int mi = 0; mi < 4; ++mi)                                \
      _Pragma("unroll")                                           \
      for (int ni = 0; ni < 2; ++ni)                              \
        acc[mi][ni] = __builtin_amdgcn_mfma_f32_16x16x32_bf16(    \
            af[4 + mi], bfv[2 + ni], acc[mi][ni], 0, 0, 0);       \
    __builtin_amdgcn_s_setprio(0);                                \
  }

#define SYNC_TILE()                                               \
  {                                                               \
    asm volatile("s_waitcnt vmcnt(0)" ::: "memory");              \
    __builtin_amdgcn_s_barrier();                                 \
    asm volatile("" ::: "memory");                                \
  }

  STAGEB(Bs0, 0);
  SYNC_TILE();

  for (int t = 0; t < 32; t += 2) {
    STAGEB(Bs1, (t + 1) * 64);
    COMPUTE(Bs0, t);
    SYNC_TILE();
    if (t + 2 < 32) STAGEB(Bs0, (t + 2) * 64);
    COMPUTE(Bs1, t + 1);
    SYNC_TILE();
  }
#undef STAGEB
#undef COMPUTE
#undef SYNC_TILE

  const int cm = (l >> 4) * 4, cn = l & 15;
  float sb[2];
#pragma unroll
  for (int ni = 0; ni < 2; ++ni)
    sb[ni] = sae_bias[bn * 128 + wn + ni * 16 + cn];
#pragma unroll
  for (int mi = 0; mi < 4; ++mi) {
#pragma unroll
    for (int r = 0; r < 4; ++r) {
      int row = bm * 128 + wm + mi * 16 + cm + r;
      float* Crow = C + (size_t)row * N + bn * 128 + wn;
#pragma unroll
      for (int ni = 0; ni < 2; ++ni)
        Crow[ni * 16 + cn] = acc[mi][ni][r] + sb[ni];
    }
  }
}

// ---------------- Encode GEMM fallback (f32, NT) ----------------
#define BM 128
#define BN 128
#define BK 32
#define LDP 136

__global__ __launch_bounds__(256) void enc_gemm_f32(
    const float* __restrict__ A, const float* __restrict__ Bw,
    const float* __restrict__ sae_bias, float* __restrict__ C,
    int M, int N, int K) {
  __shared__ __align__(16) float As[BK * LDP];
  __shared__ __align__(16) float Bs[BK * LDP];
  const int tid = threadIdx.x;
  const int bn = blockIdx.x, bm = blockIdx.y;
  const float* Ab = A + (size_t)bm * BM * K;
  const float* Bb = Bw + (size_t)bn * BN * K;
  float acc[8][8];
#pragma unroll
  for (int i = 0; i < 8; ++i)
#pragma unroll
    for (int j = 0; j < 8; ++j) acc[i][j] = 0.f;
  const int tn = tid & 15, tm = tid >> 4;
  const int lk = tid & 31;
  const int lm4 = (tid >> 5) * 4;
  for (int k0 = 0; k0 < K; k0 += BK) {
#pragma unroll
    for (int i = 0; i < 4; ++i) {
      int mb = i * 32 + lm4;
      float a0 = Ab[(size_t)(mb + 0) * K + k0 + lk];
      float a1 = Ab[(size_t)(mb + 1) * K + k0 + lk];
      float a2 = Ab[(size_t)(mb + 2) * K + k0 + lk];
      float a3 = Ab[(size_t)(mb + 3) * K + k0 + lk];
      *reinterpret_cast<float4*>(&As[lk * LDP + mb]) = make_float4(a0, a1, a2, a3);
      float b0 = Bb[(size_t)(mb + 0) * K + k0 + lk];
      float b1 = Bb[(size_t)(mb + 1) * K + k0 + lk];
      float b2 = Bb[(size_t)(mb + 2) * K + k0 + lk];
      float b3 = Bb[(size_t)(mb + 3) * K + k0 + lk];
      *reinterpret_cast<float4*>(&Bs[lk * LDP + mb]) = make_float4(b0, b1, b2, b3);
    }
    __syncthreads();
#pragma unroll 8
    for (int kk = 0; kk < BK; ++kk) {
      float4 a0 = *reinterpret_cast<const float4*>(&As[kk * LDP + tm * 4]);
      float4 a1 = *reinterpret_cast<const float4*>(&As[kk * LDP + tm * 4 + 64]);
      float4 b0 = *reinterpret_cast<const float4*>(&Bs[kk * LDP + tn * 4]);
      float4 b1 = *reinterpret_cast<const float4*>(&Bs[kk * LDP + tn * 4 + 64]);
      float av[8] = {a0.x, a0.y, a0.z, a0.w, a1.x, a1.y, a1.z, a1.w};
      float bv[8] = {b0.x, b0.y, b0.z, b0.w, b1.x, b1.y, b1.z, b1.w};
#pragma unroll
      for (int ii = 0; ii < 8; ++ii)
#pragma unroll
        for (int jj = 0; jj < 8; ++jj)
          acc[ii][jj] = fmaf(av[ii], bv[jj], acc[ii][jj]);
    }
    __syncthreads();
  }
  float4 sb0 = *reinterpret_cast<const float4*>(sae_bias + bn * BN + tn * 4);
  float4 sb1 = *reinterpret_cast<const float4*>(sae_bias + bn * BN + tn * 4 + 64);
#pragma unroll
  for (int ii = 0; ii < 8; ++ii) {
    int row = bm * BM + (ii < 4 ? tm * 4 + ii : 64 + tm * 4 + ii - 4);
    float* Crow = C + (size_t)row * N + bn * BN;
    float4 o0 = make_float4(acc[ii][0] + sb0.x, acc[ii][1] + sb0.y,
                            acc[ii][2] + sb0.z, acc[ii][3] + sb0.w);
    float4 o1 = make_float4(acc[ii][4] + sb1.x, acc[ii][5] + sb1.y,
                            acc[ii][6] + sb1.z, acc[ii][7] + sb1.w);
    *reinterpret_cast<float4*>(Crow + tn * 4) = o0;
    *reinterpret_cast<float4*>(Crow + tn * 4 + 64) = o1;
  }
}

// ---------------- TopK: monotonic f32->u32 map ----------------
__device__ __forceinline__ unsigned mapf(float f) {
  unsigned u = __float_as_uint(f);
  return (u & 0x80000000u) ? ~u : (u | 0x80000000u);
}

// radix-select: level0 = 12-bit (4096-bin) histogram + parallel suffix scan;
// early-exit once candidate count <= CAP. Collect pass stores idx+value.
// Latents zeroing is done by an up-front hipMemsetAsync (pure-read kernel).
__global__ __launch_bounds__(256) void topk_select(
    const float* __restrict__ preact,
    const int* __restrict__ kp, int* __restrict__ cand, float* __restrict__ candv,
    int* __restrict__ candcnt, int S) {
  const int b = blockIdx.x, tid = threadIdx.x;
  const float4* row4 = reinterpret_cast<const float4*>(preact + (size_t)b * S);
  __shared__ int hist[4096];
  __shared__ int tsum[256];
  __shared__ unsigned sh_pref, sh_thr;
  __shared__ int sh_done, sh_cum, sh_cnt;
  int K = kp[0]; if (K > 192) K = 192;
  const int r = K + PAD;
  if (tid == 0) { sh_done = 0; sh_pref = 0; sh_cum = 0; }
  for (int level = 0; level < 3; ++level) {
    __syncthreads();
    if (sh_done) break;
    const int shift = (level == 0) ? 20 : (level == 1) ? 8 : 0;
    const int width = (level == 2) ? 8 : 12;
    const int nb = 1 << width;
    const unsigned mask = (unsigned)nb - 1;
    for (int i = tid; i < nb; i += 256) hist[i] = 0;
    __syncthreads();
    const unsigned pref = sh_pref;
    for (int i = tid; i < S / 4; i += 256) {
      float4 v = row4[i];
      unsigned uu[4] = {mapf(v.x), mapf(v.y), mapf(v.z), mapf(v.w)};
#pragma unroll
      for (int q = 0; q < 4; ++q) {
        bool ok = (level == 0) || ((uu[q] >> (shift + width)) == pref);
        if (ok) atomicAdd(&hist[(uu[q] >> shift) & mask], 1);
      }
    }
    __syncthreads();
    const int per = nb >> 8;   // bins per thread (16 or 1)
    int myts = 0;
#pragma unroll 4
    for (int j = 0; j < per; ++j) myts += hist[tid * per + j];
    tsum[tid] = myts;
    __syncthreads();
    // inclusive suffix sum over 256 threads
    for (int o = 1; o < 256; o <<= 1) {
      int v_ = (tid + o < 256) ? tsum[tid + o] : 0;
      __syncthreads();
      tsum[tid] += v_;
      __syncthreads();
    }
    const int rr = r - sh_cum;
    const int sufIncl = tsum[tid];
    const int sufExcl = sufIncl - myts;
    if (sufExcl < rr && rr <= sufIncl) {     // exactly one thread
      int running = sufExcl;
      for (int j = per - 1; j >= 0; --j) {
        int bb = tid * per + j;
        int c = hist[bb];
        if (running + c >= rr) {
          unsigned npref = (sh_pref << width) | (unsigned)bb;
          int candTotal = sh_cum + running + c;
          sh_pref = npref;
          sh_cum += running;
          if (candTotal <= CAP || level == 2) { sh_thr = npref << shift; sh_done = 1; }
          break;
        }
        running += c;
      }
    }
  }
  __syncthreads();
  const unsigned T = sh_thr;
  if (tid == 0) sh_cnt = 0;
  __syncthreads();
  for (int i = tid; i < S / 4; i += 256) {
    float4 v = row4[i];
    unsigned uu[4] = {mapf(v.x), mapf(v.y), mapf(v.z), mapf(v.w)};
    float vv[4] = {v.x, v.y, v.z, v.w};
#pragma unroll
    for (int q = 0; q < 4; ++q) {
      if (uu[q] >= T) {
        int p = atomicAdd(&sh_cnt, 1);
        if (p < CAP) { cand[(size_t)b * CAP + p] = i * 4 + q; candv[(size_t)b * CAP + p] = vv[q]; }
      }
    }
  }
  __syncthreads();
  if (tid == 0) candcnt[b] = (sh_cnt < CAP) ? sh_cnt : CAP;
}

// sort candidates by approx value; f64-recompute ONLY the ambiguous window
// around the rank-K boundary; emit top-K set (certain-in with approx values,
// boundary resolved by f64). Fallback: full f64 recompute if window overflows.
__global__ __launch_bounds__(256) void topk_refine(
    const float* __restrict__ a, const float* __restrict__ W_enc,
    const float* __restrict__ sae_bias, const int* __restrict__ kp,
    const int* __restrict__ cand, const float* __restrict__ candv,
    const int* __restrict__ candcnt,
    float* __restrict__ latents, int* __restrict__ out_idx, float* __restrict__ out_val,
    int D, int S) {
  const int b = blockIdx.x, tid = threadIdx.x;
  __shared__ float sv[256];
  __shared__ int si[256];
  __shared__ double sv64[256];
  __shared__ double av[AMBCAP];
  __shared__ int agid[AMBCAP];
  __shared__ int sh_amb, sh_nin;
  int K = kp[0]; if (K > 192) K = 192;
  const int cnt = candcnt[b];
  const int wave = tid >> 6, lane = tid & 63;
  const float4* ar4 = reinterpret_cast<const float4*>(a + (size_t)b * D);
  const int nit = D / 256;

  if (tid < cnt) { sv[tid] = candv[(size_t)b * CAP + tid]; si[tid] = cand[(size_t)b * CAP + tid]; }
  else { sv[tid] = -3.0e38f; si[tid] = 0x7FFFFFFF; }
  __syncthreads();
  // bitonic sort 256: (value desc, idx asc)
  for (int ksz = 2; ksz <= 256; ksz <<= 1) {
    for (int j = ksz >> 1; j > 0; j >>= 1) {
      int ixj = tid ^ j;
      if (ixj > tid) {
        float v1 = sv[tid], v2 = sv[ixj];
        int i1 = si[tid], i2 = si[ixj];
        bool dirDesc = ((tid & ksz) == 0);
        bool firstBetter = (v1 > v2) || (v1 == v2 && i1 < i2);
        if (dirDesc ? (!firstBetter) : firstBetter) {
          sv[tid] = v2; sv[ixj] = v1; si[tid] = i2; si[ixj] = i1;
        }
      }
      __syncthreads();
    }
  }
  const float vK = sv[K - 1];
  if (tid == 0) { sh_amb = 0; sh_nin = 0; }
  __syncthreads();
  bool isC = tid < cnt;
  if (isC && (sv[tid] > vK + DELTA)) atomicAdd(&sh_nin, 1);
  if (isC && fabsf(sv[tid] - vK) <= DELTA) {
    int p = atomicAdd(&sh_amb, 1);
    if (p < AMBCAP) agid[p] = si[tid];
  }
  __syncthreads();
  const int nAmb = sh_amb, nIn = sh_nin;

  if (nAmb <= AMBCAP) {
    // ---- fast path: f64 only for the ambiguous window ----
    for (int c = wave; c < nAmb; c += 4) {
      int sidx = agid[c];
      const float4* wr4 = reinterpret_cast<const float4*>(W_enc + (size_t)sidx * D);
      double acc = 0.0;
      for (int m = 0; m < nit; ++m) {
        float4 a_ = ar4[m * 64 + lane];
        float4 w_ = wr4[m * 64 + lane];
        acc += (double)a_.x * w_.x + (double)a_.y * w_.y
             + (double)a_.z * w_.z + (double)a_.w * w_.w;
      }
#pragma unroll
      for (int off = 1; off < 64; off <<= 1) acc += __shfl_xor(acc, off);
      if (lane == 0) av[c] = acc + (double)sae_bias[sidx];
    }
    __syncthreads();
    if (tid < AMBCAP && tid >= nAmb) { av[tid] = -1.0e300; agid[tid] = 0x7FFFFFFF; }
    __syncthreads();
    // bitonic sort AMBCAP slots by (f64 desc, idx asc)
    for (int ksz = 2; ksz <= AMBCAP; ksz <<= 1) {
      for (int j = ksz >> 1; j > 0; j >>= 1) {
        int ixj = tid ^ j;
        if (tid < AMBCAP && ixj > tid) {
          double v1 = av[tid], v2 = av[ixj];
          int i1 = agid[tid], i2 = agid[ixj];
          bool dirDesc = ((tid & ksz) == 0);
          bool firstBetter = (v1 > v2) || (v1 == v2 && i1 < i2);
          if (dirDesc ? (!firstBetter) : firstBetter) {
            av[tid] = v2; av[ixj] = v1; agid[tid] = i2; agid[ixj] = i1;
          }
        }
        __syncthreads();
      }
    }
    if (tid < K) {
      int gidx; float val;
      if (tid < nIn) { gidx = si[tid]; val = sv[tid]; }
      else { int c = tid - nIn; gidx = agid[c]; val = (float)av[c]; }
      val = fmaxf(val, 0.f);
      latents[(size_t)b * S + gidx] = val;
      out_idx[(size_t)b * 256 + tid] = gidx;
      out_val[(size_t)b * 256 + tid] = val;
    }
  } else {
    // ---- slow path (vestigial safety): full f64 recompute + sort ----
    for (int c = wave; c < cnt; c += 4) {
      int sidx = si[c];
      const float4* wr4 = reinterpret_cast<const float4*>(W_enc + (size_t)sidx * D);
      double acc = 0.0;
      for (int m = 0; m < nit; ++m) {
        float4 a_ = ar4[m * 64 + lane];
        float4 w_ = wr4[m * 64 + lane];
        acc += (double)a_.x * w_.x + (double)a_.y * w_.y
             + (double)a_.z * w_.z + (double)a_.w * w_.w;
      }
#pragma unroll
      for (int off = 1; off < 64; off <<= 1) acc += __shfl_xor(acc, off);
      if (lane == 0) sv64[c] = acc + (double)sae_bias[sidx];
    }
    __syncthreads();
    if (tid >= cnt) { sv64[tid] = -1.0e300; si[tid] = 0x7FFFFFFF; }
    __syncthreads();
    for (int ksz = 2; ksz <= 256; ksz <<= 1) {
      for (int j = ksz >> 1; j > 0; j >>= 1) {
        int ixj = tid ^ j;
        if (ixj > tid) {
          double v1 = sv64[tid], v2 = sv64[ixj];
          int i1 = si[tid], i2 = si[ixj];
          bool dirDesc = ((tid & ksz) == 0);
          bool firstBetter = (v1 > v2) || (v1 == v2 && i1 < i2);
          if (dirDesc ? (!firstBetter) : firstBetter) {
            sv64[tid] = v2; sv64[ixj] = v1; si[tid] = i2; si[ixj] = i1;
          }
        }
        __syncthreads();
      }
    }
    if (tid < K) {
      int idx = si[tid];
      float rv = fmaxf((float)sv64[tid], 0.f);
      latents[(size_t)b * S + idx] = rv;
      out_idx[(size_t)b * 256 + tid] = idx;
      out_val[(size_t)b * 256 + tid] = rv;
    }
  }
}

// ---------------- W_dec [D,S] f32 -> WdTh [S,D] bf16 ----------------
__global__ __launch_bounds__(256) void transpose_cvt(const float* __restrict__ src,
    unsigned short* __restrict__ dst, int D, int S) {
  __shared__ float t[32][33];
  int s0 = blockIdx.x * 32, d0 = blockIdx.y * 32;
  int tx = threadIdx.x & 31, ty = threadIdx.x >> 5;
#pragma unroll
  for (int i = 0; i < 32; i += 8)
    t[ty + i][tx] = src[(size_t)(d0 + ty + i) * S + s0 + tx];
  __syncthreads();
#pragma unroll
  for (int i = 0; i < 32; i += 8)
    dst[(size_t)(s0 + ty + i) * D + d0 + tx] = f2bf(t[tx][ty + i]);
}

// ---------------- Decode (bf16 gather, 512 thr x 4 cols): recons = (lat @ WdTh + pre_bias)*std + mean ----------------
__global__ __launch_bounds__(512) void decode_bf16(
    const unsigned short* __restrict__ WdTh, const float* __restrict__ pre_bias,
    const float* __restrict__ stats, const int* __restrict__ kp,
    const int* __restrict__ out_idx, const float* __restrict__ out_val,
    float* __restrict__ recons, int D) {
  const int b = blockIdx.x, tid = threadIdx.x;
  __shared__ int sidx[192];
  __shared__ float sval[192];
  int K = kp[0]; if (K > 192) K = 192;
  if (tid < K) { sidx[tid] = out_idx[(size_t)b * 256 + tid]; sval[tid] = out_val[(size_t)b * 256 + tid]; }
  __syncthreads();
  const int c0 = tid * 4;
  float4 p0 = *reinterpret_cast<const float4*>(pre_bias + c0);
  float acc0 = p0.x, acc1 = p0.y, acc2 = p0.z, acc3 = p0.w;
  for (int j = 0; j < K; ++j) {
    float v = sval[j];
    uint2 wv = *reinterpret_cast<const uint2*>(WdTh + (size_t)sidx[j] * D + c0);
    acc0 = fmaf(v, bf2f((unsigned short)(wv.x & 0xffff)), acc0);
    acc1 = fmaf(v, bf2f((unsigned short)(wv.x >> 16)),    acc1);
    acc2 = fmaf(v, bf2f((unsigned short)(wv.y & 0xffff)), acc2);
    acc3 = fmaf(v, bf2f((unsigned short)(wv.y >> 16)),    acc3);
  }
  float mean = stats[2 * b], sd = stats[2 * b + 1];
  float4 o = make_float4(acc0 * sd + mean, acc1 * sd + mean,
                         acc2 * sd + mean, acc3 * sd + mean);
  *reinterpret_cast<float4*>(recons + (size_t)b * D + c0) = o;
}

// fallback (strided gather from W_dec [D,S])
__global__ __launch_bounds__(256) void decode_fb(
    const float* __restrict__ Wd, const float* __restrict__ pre_bias,
    const float* __restrict__ stats, const int* __restrict__ kp,
    const int* __restrict__ out_idx, const float* __restrict__ out_val,
    float* __restrict__ recons, int D, int S) {
  const int b = blockIdx.x, tid = threadIdx.x;
  __shared__ int sidx[192];
  __shared__ float sval[192];
  int K = kp[0]; if (K > 192) K = 192;
  if (tid < K) { sidx[tid] = out_idx[(size_t)b * 256 + tid]; sval[tid] = out_val[(size_t)b * 256 + tid]; }
  __syncthreads();
  for (int d = tid; d < D; d += 256) {
    float acc = pre_bias[d];
    for (int j = 0; j < K; ++j)
      acc = fmaf(sval[j], Wd[(size_t)d * S + sidx[j]], acc);
    recons[(size_t)b * D + d] = acc * stats[2 * b + 1] + stats[2 * b];
  }
}

extern "C" void kernel_launch(void* const* d_in, const int* in_sizes, int n_in,
                              void* d_out, int out_size, void* d_ws, size_t ws_size,
                              hipStream_t stream) {
  const float* x        = (const float*)d_in[0];
  const float* W_enc    = (const float*)d_in[1];
  const float* W_dec    = (const float*)d_in[2];
  const float* pre_bias = (const float*)d_in[3];
  const float* sae_bias = (const float*)d_in[4];
  const int*   kp       = (const int*)d_in[5];
  const int D = in_sizes[3];
  const int S = in_sizes[4];
  const int B = in_sizes[0] / D;

  float* out_pre = (float*)d_out;
  float* out_lat = out_pre + (size_t)B * S;
  float* out_rec = out_lat + (size_t)B * S;

  char* ws = (char*)d_ws;
  size_t off = 0;
  float* a = (float*)(ws + off);        off += (size_t)B * D * 4;
  float* stats = (float*)(ws + off);    off += (size_t)B * 2 * 4;
  int* cand = (int*)(ws + off);         off += (size_t)B * CAP * 4;
  float* candv = (float*)(ws + off);    off += (size_t)B * CAP * 4;
  int* candcnt = (int*)(ws + off);      off += (size_t)B * 4;
  int* oidx = (int*)(ws + off);         off += (size_t)B * 256 * 4;
  float* oval = (float*)(ws + off);     off += (size_t)B * 256 * 4;
  off = (off + 255) & ~(size_t)255;
  unsigned short* A2 = (unsigned short*)(ws + off);
  size_t offA2F = off + (size_t)B * D * 2;
  unsigned short* A2F = (unsigned short*)(ws + offA2F);
  size_t offW2 = offA2F + (size_t)B * D * 2;
  unsigned short* W2 = (unsigned short*)(ws + offW2);
  size_t offWdT = offW2 + (size_t)S * D * 2;
  unsigned short* WdTh = (unsigned short*)(ws + offWdT);
  size_t offEnd = offWdT + (size_t)S * D * 2;
  bool useBf16 = (D == 2048) && (B % 128 == 0) && (B % 16 == 0) &&
                 (S % 128 == 0) && (S % 32 == 0) && (ws_size >= offEnd);

  // zero latents up-front (DMA fill) so topk_select is a pure-read kernel
  hipMemsetAsync(out_lat, 0, (size_t)B * S * 4, stream);

  if (useBf16) {
    ln_kernel<<<B, 256, 0, stream>>>(x, pre_bias, a, A2, stats, D);
    repack_a<<<B / 16, 256, 0, stream>>>(A2, A2F);
    cvt_w_kernel<<<S, 256, 0, stream>>>(W_enc, W2, D);
    enc_gemm_bf16<<<dim3(S / 128, B / 128), 512, 0, stream>>>(A2F, W2, sae_bias, out_pre, B, S);
    transpose_cvt<<<dim3(S / 32, D / 32), 256, 0, stream>>>(W_dec, WdTh, D, S);
    topk_select<<<B, 256, 0, stream>>>(out_pre, kp, cand, candv, candcnt, S);
    topk_refine<<<B, 256, 0, stream>>>(a, W_enc, sae_bias, kp, cand, candv, candcnt,
                                       out_lat, oidx, oval, D, S);
    decode_bf16<<<B, 512, 0, stream>>>(WdTh, pre_bias, stats, kp, oidx, oval, out_rec, D);
  } else {
    ln_kernel<<<B, 256, 0, stream>>>(x, pre_bias, a, nullptr, stats, D);
    enc_gemm_f32<<<dim3(S / BN, B / BM), 256, 0, stream>>>(a, W_enc, sae_bias, out_pre, B, S, D);
    topk_select<<<B, 256, 0, stream>>>(out_pre, kp, cand, candv, candcnt, S);
    topk_refine<<<B, 256, 0, stream>>>(a, W_enc, sae_bias, kp, cand, candv, candcnt,
                                       out_lat, oidx, oval, D, S);
    decode_fb<<<B, 256, 0, stream>>>(W_dec, pre_bias, stats, kp, oidx, oval, out_rec, D, S);
  }
}

// Round 14
// 846.377 us; speedup vs baseline: 1.0911x; 1.0911x over previous
//
#include <hip/hip_runtime.h>
#include <cstdint>
#include <cstddef>

#define EPSV 1e-5f
#define CAP 224      // candidate list capacity per row (>= K+PAD for K<=192)
#define PAD 16       // extra candidates beyond k
#define DELTA 0.03f  // ambiguity half-window >= 2*E_max(approx err ~8e-3); 0.012 FAILED R7, 0.02/0.03 passed
#define AMBCAP 64

// ---------- bf16 helpers (bit-level, RNE) ----------
__device__ __forceinline__ unsigned short f2bf(float f) {
  unsigned u = __float_as_uint(f);
  unsigned r = (u + 0x7FFFu + ((u >> 16) & 1u)) >> 16;
  return (unsigned short)r;
}
__device__ __forceinline__ float bf2f(unsigned short h) {
  return __uint_as_float(((unsigned)h) << 16);
}

// ---------------- LayerNorm: a = (x-mean)/(std+eps) - pre_bias; also emit bf16 hi panel ----------------
__global__ __launch_bounds__(256) void ln_kernel(const float* __restrict__ x,
    const float* __restrict__ pre_bias, float* __restrict__ a,
    unsigned short* __restrict__ A2,   // [B][2048] bf16 (may be null)
    float* __restrict__ stats, int D) {
  const int b = blockIdx.x;
  const int tid = threadIdx.x;
  const float4* x4 = reinterpret_cast<const float4*>(x + (size_t)b * D);
  const float4* pb4 = reinterpret_cast<const float4*>(pre_bias);
  float4* a4 = reinterpret_cast<float4*>(a + (size_t)b * D);
  float4 v0 = x4[tid], v1 = x4[tid + 256];
  float s = v0.x + v0.y + v0.z + v0.w + v1.x + v1.y + v1.z + v1.w;
  float ss = v0.x*v0.x + v0.y*v0.y + v0.z*v0.z + v0.w*v0.w
           + v1.x*v1.x + v1.y*v1.y + v1.z*v1.z + v1.w*v1.w;
#pragma unroll
  for (int off = 1; off < 64; off <<= 1) { s += __shfl_xor(s, off); ss += __shfl_xor(ss, off); }
  __shared__ float wsum[4], wssq[4], bmean, bstd;
  int wave = tid >> 6;
  if ((tid & 63) == 0) { wsum[wave] = s; wssq[wave] = ss; }
  __syncthreads();
  if (tid == 0) {
    float S1 = wsum[0] + wsum[1] + wsum[2] + wsum[3];
    float S2 = wssq[0] + wssq[1] + wssq[2] + wssq[3];
    float mean = S1 / (float)D;
    float var = (S2 - (float)D * mean * mean) / (float)(D - 1);
    float sd = sqrtf(fmaxf(var, 0.f));
    bmean = mean; bstd = sd;
    stats[2*b] = mean; stats[2*b+1] = sd;
  }
  __syncthreads();
  float mean = bmean, rstd = 1.f / (bstd + EPSV);
  float4 p0 = pb4[tid], p1 = pb4[tid + 256];
  float4 o0, o1;
  o0.x = (v0.x - mean) * rstd - p0.x; o0.y = (v0.y - mean) * rstd - p0.y;
  o0.z = (v0.z - mean) * rstd - p0.z; o0.w = (v0.w - mean) * rstd - p0.w;
  o1.x = (v1.x - mean) * rstd - p1.x; o1.y = (v1.y - mean) * rstd - p1.y;
  o1.z = (v1.z - mean) * rstd - p1.z; o1.w = (v1.w - mean) * rstd - p1.w;
  a4[tid] = o0; a4[tid + 256] = o1;
  if (A2) {
    unsigned short* row = A2 + (size_t)b * 2048;
    ushort4 h0 = make_ushort4(f2bf(o0.x), f2bf(o0.y), f2bf(o0.z), f2bf(o0.w));
    ushort4 h1 = make_ushort4(f2bf(o1.x), f2bf(o1.y), f2bf(o1.z), f2bf(o1.w));
    *reinterpret_cast<ushort4*>(row + tid * 4) = h0;
    *reinterpret_cast<ushort4*>(row + 1024 + tid * 4) = h1;
  }
}

// ---------------- W_enc [S][2048] f32 -> W2 [S][2048] bf16 ----------------
__global__ __launch_bounds__(256) void cvt_w_kernel(const float* __restrict__ W,
    unsigned short* __restrict__ W2, int D) {
  const int s = blockIdx.x, tid = threadIdx.x;
  const float4* w4 = reinterpret_cast<const float4*>(W + (size_t)s * D);
  unsigned short* row = W2 + (size_t)s * D;
  float4 v0 = w4[tid * 2], v1 = w4[tid * 2 + 1];
  uint4 p;
  p.x = (unsigned)f2bf(v0.x) | ((unsigned)f2bf(v0.y) << 16);
  p.y = (unsigned)f2bf(v0.z) | ((unsigned)f2bf(v0.w) << 16);
  p.z = (unsigned)f2bf(v1.x) | ((unsigned)f2bf(v1.y) << 16);
  p.w = (unsigned)f2bf(v1.z) | ((unsigned)f2bf(v1.w) << 16);
  *reinterpret_cast<uint4*>(row + tid * 8) = p;
}

// ---------------- bf16 MFMA encode GEMM: C = A·W^T + sae_bias, K=2048 ----------------
typedef __attribute__((ext_vector_type(8))) short bf8;
typedef __attribute__((ext_vector_type(4))) float f32x4;

__device__ __forceinline__ void gload16(const void* g, void* l) {
  __builtin_amdgcn_global_load_lds(
      (const __attribute__((address_space(1))) unsigned int*)g,
      (__attribute__((address_space(3))) unsigned int*)l,
      16, 0, 0);
}

// R14 = exact R12 revert (verified best: 350us GEMM). 512 threads / 8 waves
// (2M x 4N), wave tile 64x32, A+B staged in LDS, 2-phase dbuf
// (STAGE-next-before-COMPUTE-cur, vmcnt(0)+raw barrier), T2 both-sides
// swizzle, T5 setprio, batched fragment reads (all 24 ds_reads up-front).
// Natural grid order (bn%8 already partitions B across XCDs; R11 swizzle
// doubled HBM). Register-direct A variants (R10 flat, R13 fragmentized)
// both REGRESSED: operand data must flow global->LDS->regs in this
// 2-barrier structure or memory latency lands unhidden inside COMPUTE.
__global__ __launch_bounds__(512) void enc_gemm_bf16(
    const unsigned short* __restrict__ A2,   // [M][2048]
    const unsigned short* __restrict__ W2,   // [N][2048]
    const float* __restrict__ sae_bias,
    float* __restrict__ C, int M, int N) {
  __shared__ __align__(16) short As0[128 * 64];
  __shared__ __align__(16) short Bs0[128 * 64];
  __shared__ __align__(16) short As1[128 * 64];
  __shared__ __align__(16) short Bs1[128 * 64];
  const int tid = threadIdx.x;
  const int bn = blockIdx.x, bm = blockIdx.y;
  const int w = tid >> 6, l = tid & 63;

  // staging: 1024 16B-slots per matrix; 2 rounds of 512 threads
  const unsigned short* gA[2];
  const unsigned short* gB[2];
  int ldsSlot[2];
#pragma unroll
  for (int r = 0; r < 2; ++r) {
    int slot = r * 512 + tid;
    int row = slot >> 3, unit = slot & 7;
    int gcol = (unit ^ (row & 7)) * 8;      // pre-swizzled global 16B unit
    gA[r] = A2 + (size_t)(bm * 128 + row) * 2048 + gcol;
    gB[r] = W2 + (size_t)(bn * 128 + row) * 2048 + gcol;
    ldsSlot[r] = slot * 8;                  // linear LDS dest (elems)
  }

  // wave tile: 64(M) x 32(N)
  const int wm = (w >> 2) * 64, wn = (w & 3) * 32;
  const int r15 = l & 15, b7 = l & 7, u = l >> 4;
  const int colks0 = ((u + 0) ^ b7) * 8;    // ks=0 physical col offset (elems)
  const int colks1 = ((u + 4) ^ b7) * 8;    // ks=1
  const int baseA = (wm + r15) * 64;
  const int baseB = (wn + r15) * 64;

  f32x4 acc[4][2];
#pragma unroll
  for (int mi = 0; mi < 4; ++mi)
#pragma unroll
    for (int ni = 0; ni < 2; ++ni) acc[mi][ni] = (f32x4){0.f, 0.f, 0.f, 0.f};

#define STAGE(Adst, Bdst, koff)                                   \
  {                                                               \
    _Pragma("unroll")                                             \
    for (int r = 0; r < 2; ++r) {                                 \
      gload16(gA[r] + (koff), &(Adst)[ldsSlot[r]]);               \
      gload16(gB[r] + (koff), &(Bdst)[ldsSlot[r]]);               \
    }                                                             \
  }

#define COMPUTE(Asrc, Bsrc)                                       \
  {                                                               \
    bf8 af[8], bfv[4];                                            \
    _Pragma("unroll")                                             \
    for (int mi = 0; mi < 4; ++mi) {                              \
      af[mi]     = *reinterpret_cast<const bf8*>(&(Asrc)[baseA + mi * 1024 + colks0]); \
      af[4 + mi] = *reinterpret_cast<const bf8*>(&(Asrc)[baseA + mi * 1024 + colks1]); \
    }                                                             \
    _Pragma("unroll")                                             \
    for (int ni = 0; ni < 2; ++ni) {                              \
      bfv[ni]     = *reinterpret_cast<const bf8*>(&(Bsrc)[baseB + ni * 1024 + colks0]); \
      bfv[2 + ni] = *reinterpret_cast<const bf8*>(&(Bsrc)[baseB + ni * 1024 + colks1]); \
    }                                                             \
    __builtin_amdgcn_s_setprio(1);                                \
    _Pragma("unroll")                                             \
    for (int mi = 0; mi < 4; ++mi)                                \
      _Pragma("unroll")                                           \
      for (int ni = 0; ni < 2; ++ni)                              \
        acc[mi][ni] = __builtin_amdgcn_mfma_f32_16x16x32_bf16(    \
            af[mi], bfv[ni], acc[mi][ni], 0, 0, 0);               \
    _Pragma("unroll")                                             \
    for (int mi = 0; mi < 4; ++mi)                                \
      _Pragma("unroll")                                           \
      for (int ni = 0; ni < 2; ++ni)                              \
        acc[mi][ni] = __builtin_amdgcn_mfma_f32_16x16x32_bf16(    \
            af[4 + mi], bfv[2 + ni], acc[mi][ni], 0, 0, 0);       \
    __builtin_amdgcn_s_setprio(0);                                \
  }

#define SYNC_TILE()                                               \
  {                                                               \
    asm volatile("s_waitcnt vmcnt(0)" ::: "memory");              \
    __builtin_amdgcn_s_barrier();                                 \
    asm volatile("" ::: "memory");                                \
  }

  STAGE(As0, Bs0, 0);
  SYNC_TILE();

  for (int t = 0; t < 32; t += 2) {
    STAGE(As1, Bs1, (t + 1) * 64);
    COMPUTE(As0, Bs0);
    SYNC_TILE();
    if (t + 2 < 32) STAGE(As0, Bs0, (t + 2) * 64);
    COMPUTE(As1, Bs1);
    SYNC_TILE();
  }
#undef STAGE
#undef COMPUTE
#undef SYNC_TILE

  const int cm = (l >> 4) * 4, cn = l & 15;
  float sb[2];
#pragma unroll
  for (int ni = 0; ni < 2; ++ni)
    sb[ni] = sae_bias[bn * 128 + wn + ni * 16 + cn];
#pragma unroll
  for (int mi = 0; mi < 4; ++mi) {
#pragma unroll
    for (int r = 0; r < 4; ++r) {
      int row = bm * 128 + wm + mi * 16 + cm + r;
      float* Crow = C + (size_t)row * N + bn * 128 + wn;
#pragma unroll
      for (int ni = 0; ni < 2; ++ni)
        Crow[ni * 16 + cn] = acc[mi][ni][r] + sb[ni];
    }
  }
}

// ---------------- Encode GEMM fallback (f32, NT) ----------------
#define BM 128
#define BN 128
#define BK 32
#define LDP 136

__global__ __launch_bounds__(256) void enc_gemm_f32(
    const float* __restrict__ A, const float* __restrict__ Bw,
    const float* __restrict__ sae_bias, float* __restrict__ C,
    int M, int N, int K) {
  __shared__ __align__(16) float As[BK * LDP];
  __shared__ __align__(16) float Bs[BK * LDP];
  const int tid = threadIdx.x;
  const int bn = blockIdx.x, bm = blockIdx.y;
  const float* Ab = A + (size_t)bm * BM * K;
  const float* Bb = Bw + (size_t)bn * BN * K;
  float acc[8][8];
#pragma unroll
  for (int i = 0; i < 8; ++i)
#pragma unroll
    for (int j = 0; j < 8; ++j) acc[i][j] = 0.f;
  const int tn = tid & 15, tm = tid >> 4;
  const int lk = tid & 31;
  const int lm4 = (tid >> 5) * 4;
  for (int k0 = 0; k0 < K; k0 += BK) {
#pragma unroll
    for (int i = 0; i < 4; ++i) {
      int mb = i * 32 + lm4;
      float a0 = Ab[(size_t)(mb + 0) * K + k0 + lk];
      float a1 = Ab[(size_t)(mb + 1) * K + k0 + lk];
      float a2 = Ab[(size_t)(mb + 2) * K + k0 + lk];
      float a3 = Ab[(size_t)(mb + 3) * K + k0 + lk];
      *reinterpret_cast<float4*>(&As[lk * LDP + mb]) = make_float4(a0, a1, a2, a3);
      float b0 = Bb[(size_t)(mb + 0) * K + k0 + lk];
      float b1 = Bb[(size_t)(mb + 1) * K + k0 + lk];
      float b2 = Bb[(size_t)(mb + 2) * K + k0 + lk];
      float b3 = Bb[(size_t)(mb + 3) * K + k0 + lk];
      *reinterpret_cast<float4*>(&Bs[lk * LDP + mb]) = make_float4(b0, b1, b2, b3);
    }
    __syncthreads();
#pragma unroll 8
    for (int kk = 0; kk < BK; ++kk) {
      float4 a0 = *reinterpret_cast<const float4*>(&As[kk * LDP + tm * 4]);
      float4 a1 = *reinterpret_cast<const float4*>(&As[kk * LDP + tm * 4 + 64]);
      float4 b0 = *reinterpret_cast<const float4*>(&Bs[kk * LDP + tn * 4]);
      float4 b1 = *reinterpret_cast<const float4*>(&Bs[kk * LDP + tn * 4 + 64]);
      float av[8] = {a0.x, a0.y, a0.z, a0.w, a1.x, a1.y, a1.z, a1.w};
      float bv[8] = {b0.x, b0.y, b0.z, b0.w, b1.x, b1.y, b1.z, b1.w};
#pragma unroll
      for (int ii = 0; ii < 8; ++ii)
#pragma unroll
        for (int jj = 0; jj < 8; ++jj)
          acc[ii][jj] = fmaf(av[ii], bv[jj], acc[ii][jj]);
    }
    __syncthreads();
  }
  float4 sb0 = *reinterpret_cast<const float4*>(sae_bias + bn * BN + tn * 4);
  float4 sb1 = *reinterpret_cast<const float4*>(sae_bias + bn * BN + tn * 4 + 64);
#pragma unroll
  for (int ii = 0; ii < 8; ++ii) {
    int row = bm * BM + (ii < 4 ? tm * 4 + ii : 64 + tm * 4 + ii - 4);
    float* Crow = C + (size_t)row * N + bn * BN;
    float4 o0 = make_float4(acc[ii][0] + sb0.x, acc[ii][1] + sb0.y,
                            acc[ii][2] + sb0.z, acc[ii][3] + sb0.w);
    float4 o1 = make_float4(acc[ii][4] + sb1.x, acc[ii][5] + sb1.y,
                            acc[ii][6] + sb1.z, acc[ii][7] + sb1.w);
    *reinterpret_cast<float4*>(Crow + tn * 4) = o0;
    *reinterpret_cast<float4*>(Crow + tn * 4 + 64) = o1;
  }
}

// ---------------- TopK: monotonic f32->u32 map ----------------
__device__ __forceinline__ unsigned mapf(float f) {
  unsigned u = __float_as_uint(f);
  return (u & 0x80000000u) ? ~u : (u | 0x80000000u);
}

// radix-select: level0 = 12-bit (4096-bin) histogram + parallel suffix scan;
// early-exit once candidate count <= CAP. Collect pass stores idx+value.
// Latents zeroing is done by an up-front hipMemsetAsync (pure-read kernel).
__global__ __launch_bounds__(256) void topk_select(
    const float* __restrict__ preact,
    const int* __restrict__ kp, int* __restrict__ cand, float* __restrict__ candv,
    int* __restrict__ candcnt, int S) {
  const int b = blockIdx.x, tid = threadIdx.x;
  const float4* row4 = reinterpret_cast<const float4*>(preact + (size_t)b * S);
  __shared__ int hist[4096];
  __shared__ int tsum[256];
  __shared__ unsigned sh_pref, sh_thr;
  __shared__ int sh_done, sh_cum, sh_cnt;
  int K = kp[0]; if (K > 192) K = 192;
  const int r = K + PAD;
  if (tid == 0) { sh_done = 0; sh_pref = 0; sh_cum = 0; }
  for (int level = 0; level < 3; ++level) {
    __syncthreads();
    if (sh_done) break;
    const int shift = (level == 0) ? 20 : (level == 1) ? 8 : 0;
    const int width = (level == 2) ? 8 : 12;
    const int nb = 1 << width;
    const unsigned mask = (unsigned)nb - 1;
    for (int i = tid; i < nb; i += 256) hist[i] = 0;
    __syncthreads();
    const unsigned pref = sh_pref;
    for (int i = tid; i < S / 4; i += 256) {
      float4 v = row4[i];
      unsigned uu[4] = {mapf(v.x), mapf(v.y), mapf(v.z), mapf(v.w)};
#pragma unroll
      for (int q = 0; q < 4; ++q) {
        bool ok = (level == 0) || ((uu[q] >> (shift + width)) == pref);
        if (ok) atomicAdd(&hist[(uu[q] >> shift) & mask], 1);
      }
    }
    __syncthreads();
    const int per = nb >> 8;   // bins per thread (16 or 1)
    int myts = 0;
#pragma unroll 4
    for (int j = 0; j < per; ++j) myts += hist[tid * per + j];
    tsum[tid] = myts;
    __syncthreads();
    // inclusive suffix sum over 256 threads
    for (int o = 1; o < 256; o <<= 1) {
      int v_ = (tid + o < 256) ? tsum[tid + o] : 0;
      __syncthreads();
      tsum[tid] += v_;
      __syncthreads();
    }
    const int rr = r - sh_cum;
    const int sufIncl = tsum[tid];
    const int sufExcl = sufIncl - myts;
    if (sufExcl < rr && rr <= sufIncl) {     // exactly one thread
      int running = sufExcl;
      for (int j = per - 1; j >= 0; --j) {
        int bb = tid * per + j;
        int c = hist[bb];
        if (running + c >= rr) {
          unsigned npref = (sh_pref << width) | (unsigned)bb;
          int candTotal = sh_cum + running + c;
          sh_pref = npref;
          sh_cum += running;
          if (candTotal <= CAP || level == 2) { sh_thr = npref << shift; sh_done = 1; }
          break;
        }
        running += c;
      }
    }
  }
  __syncthreads();
  const unsigned T = sh_thr;
  if (tid == 0) sh_cnt = 0;
  __syncthreads();
  for (int i = tid; i < S / 4; i += 256) {
    float4 v = row4[i];
    unsigned uu[4] = {mapf(v.x), mapf(v.y), mapf(v.z), mapf(v.w)};
    float vv[4] = {v.x, v.y, v.z, v.w};
#pragma unroll
    for (int q = 0; q < 4; ++q) {
      if (uu[q] >= T) {
        int p = atomicAdd(&sh_cnt, 1);
        if (p < CAP) { cand[(size_t)b * CAP + p] = i * 4 + q; candv[(size_t)b * CAP + p] = vv[q]; }
      }
    }
  }
  __syncthreads();
  if (tid == 0) candcnt[b] = (sh_cnt < CAP) ? sh_cnt : CAP;
}

// sort candidates by approx value; f64-recompute ONLY the ambiguous window
// around the rank-K boundary; emit top-K set (certain-in with approx values,
// boundary resolved by f64). Fallback: full f64 recompute if window overflows.
__global__ __launch_bounds__(256) void topk_refine(
    const float* __restrict__ a, const float* __restrict__ W_enc,
    const float* __restrict__ sae_bias, const int* __restrict__ kp,
    const int* __restrict__ cand, const float* __restrict__ candv,
    const int* __restrict__ candcnt,
    float* __restrict__ latents, int* __restrict__ out_idx, float* __restrict__ out_val,
    int D, int S) {
  const int b = blockIdx.x, tid = threadIdx.x;
  __shared__ float sv[256];
  __shared__ int si[256];
  __shared__ double sv64[256];
  __shared__ double av[AMBCAP];
  __shared__ int agid[AMBCAP];
  __shared__ int sh_amb, sh_nin;
  int K = kp[0]; if (K > 192) K = 192;
  const int cnt = candcnt[b];
  const int wave = tid >> 6, lane = tid & 63;
  const float4* ar4 = reinterpret_cast<const float4*>(a + (size_t)b * D);
  const int nit = D / 256;

  if (tid < cnt) { sv[tid] = candv[(size_t)b * CAP + tid]; si[tid] = cand[(size_t)b * CAP + tid]; }
  else { sv[tid] = -3.0e38f; si[tid] = 0x7FFFFFFF; }
  __syncthreads();
  // bitonic sort 256: (value desc, idx asc)
  for (int ksz = 2; ksz <= 256; ksz <<= 1) {
    for (int j = ksz >> 1; j > 0; j >>= 1) {
      int ixj = tid ^ j;
      if (ixj > tid) {
        float v1 = sv[tid], v2 = sv[ixj];
        int i1 = si[tid], i2 = si[ixj];
        bool dirDesc = ((tid & ksz) == 0);
        bool firstBetter = (v1 > v2) || (v1 == v2 && i1 < i2);
        if (dirDesc ? (!firstBetter) : firstBetter) {
          sv[tid] = v2; sv[ixj] = v1; si[tid] = i2; si[ixj] = i1;
        }
      }
      __syncthreads();
    }
  }
  const float vK = sv[K - 1];
  if (tid == 0) { sh_amb = 0; sh_nin = 0; }
  __syncthreads();
  bool isC = tid < cnt;
  if (isC && (sv[tid] > vK + DELTA)) atomicAdd(&sh_nin, 1);
  if (isC && fabsf(sv[tid] - vK) <= DELTA) {
    int p = atomicAdd(&sh_amb, 1);
    if (p < AMBCAP) agid[p] = si[tid];
  }
  __syncthreads();
  const int nAmb = sh_amb, nIn = sh_nin;

  if (nAmb <= AMBCAP) {
    // ---- fast path: f64 only for the ambiguous window ----
    for (int c = wave; c < nAmb; c += 4) {
      int sidx = agid[c];
      const float4* wr4 = reinterpret_cast<const float4*>(W_enc + (size_t)sidx * D);
      double acc = 0.0;
      for (int m = 0; m < nit; ++m) {
        float4 a_ = ar4[m * 64 + lane];
        float4 w_ = wr4[m * 64 + lane];
        acc += (double)a_.x * w_.x + (double)a_.y * w_.y
             + (double)a_.z * w_.z + (double)a_.w * w_.w;
      }
#pragma unroll
      for (int off = 1; off < 64; off <<= 1) acc += __shfl_xor(acc, off);
      if (lane == 0) av[c] = acc + (double)sae_bias[sidx];
    }
    __syncthreads();
    if (tid < AMBCAP && tid >= nAmb) { av[tid] = -1.0e300; agid[tid] = 0x7FFFFFFF; }
    __syncthreads();
    // bitonic sort AMBCAP slots by (f64 desc, idx asc)
    for (int ksz = 2; ksz <= AMBCAP; ksz <<= 1) {
      for (int j = ksz >> 1; j > 0; j >>= 1) {
        int ixj = tid ^ j;
        if (tid < AMBCAP && ixj > tid) {
          double v1 = av[tid], v2 = av[ixj];
          int i1 = agid[tid], i2 = agid[ixj];
          bool dirDesc = ((tid & ksz) == 0);
          bool firstBetter = (v1 > v2) || (v1 == v2 && i1 < i2);
          if (dirDesc ? (!firstBetter) : firstBetter) {
            av[tid] = v2; av[ixj] = v1; agid[tid] = i2; agid[ixj] = i1;
          }
        }
        __syncthreads();
      }
    }
    if (tid < K) {
      int gidx; float val;
      if (tid < nIn) { gidx = si[tid]; val = sv[tid]; }
      else { int c = tid - nIn; gidx = agid[c]; val = (float)av[c]; }
      val = fmaxf(val, 0.f);
      latents[(size_t)b * S + gidx] = val;
      out_idx[(size_t)b * 256 + tid] = gidx;
      out_val[(size_t)b * 256 + tid] = val;
    }
  } else {
    // ---- slow path (vestigial safety): full f64 recompute + sort ----
    for (int c = wave; c < cnt; c += 4) {
      int sidx = si[c];
      const float4* wr4 = reinterpret_cast<const float4*>(W_enc + (size_t)sidx * D);
      double acc = 0.0;
      for (int m = 0; m < nit; ++m) {
        float4 a_ = ar4[m * 64 + lane];
        float4 w_ = wr4[m * 64 + lane];
        acc += (double)a_.x * w_.x + (double)a_.y * w_.y
             + (double)a_.z * w_.z + (double)a_.w * w_.w;
      }
#pragma unroll
      for (int off = 1; off < 64; off <<= 1) acc += __shfl_xor(acc, off);
      if (lane == 0) sv64[c] = acc + (double)sae_bias[sidx];
    }
    __syncthreads();
    if (tid >= cnt) { sv64[tid] = -1.0e300; si[tid] = 0x7FFFFFFF; }
    __syncthreads();
    for (int ksz = 2; ksz <= 256; ksz <<= 1) {
      for (int j = ksz >> 1; j > 0; j >>= 1) {
        int ixj = tid ^ j;
        if (ixj > tid) {
          double v1 = sv64[tid], v2 = sv64[ixj];
          int i1 = si[tid], i2 = si[ixj];
          bool dirDesc = ((tid & ksz) == 0);
          bool firstBetter = (v1 > v2) || (v1 == v2 && i1 < i2);
          if (dirDesc ? (!firstBetter) : firstBetter) {
            sv64[tid] = v2; sv64[ixj] = v1; si[tid] = i2; si[ixj] = i1;
          }
        }
        __syncthreads();
      }
    }
    if (tid < K) {
      int idx = si[tid];
      float rv = fmaxf((float)sv64[tid], 0.f);
      latents[(size_t)b * S + idx] = rv;
      out_idx[(size_t)b * 256 + tid] = idx;
      out_val[(size_t)b * 256 + tid] = rv;
    }
  }
}

// ---------------- W_dec [D,S] f32 -> WdTh [S,D] bf16 ----------------
__global__ __launch_bounds__(256) void transpose_cvt(const float* __restrict__ src,
    unsigned short* __restrict__ dst, int D, int S) {
  __shared__ float t[32][33];
  int s0 = blockIdx.x * 32, d0 = blockIdx.y * 32;
  int tx = threadIdx.x & 31, ty = threadIdx.x >> 5;
#pragma unroll
  for (int i = 0; i < 32; i += 8)
    t[ty + i][tx] = src[(size_t)(d0 + ty + i) * S + s0 + tx];
  __syncthreads();
#pragma unroll
  for (int i = 0; i < 32; i += 8)
    dst[(size_t)(s0 + ty + i) * D + d0 + tx] = f2bf(t[tx][ty + i]);
}

// ---------------- Decode (bf16 gather, 512 thr x 4 cols): recons = (lat @ WdTh + pre_bias)*std + mean ----------------
__global__ __launch_bounds__(512) void decode_bf16(
    const unsigned short* __restrict__ WdTh, const float* __restrict__ pre_bias,
    const float* __restrict__ stats, const int* __restrict__ kp,
    const int* __restrict__ out_idx, const float* __restrict__ out_val,
    float* __restrict__ recons, int D) {
  const int b = blockIdx.x, tid = threadIdx.x;
  __shared__ int sidx[192];
  __shared__ float sval[192];
  int K = kp[0]; if (K > 192) K = 192;
  if (tid < K) { sidx[tid] = out_idx[(size_t)b * 256 + tid]; sval[tid] = out_val[(size_t)b * 256 + tid]; }
  __syncthreads();
  const int c0 = tid * 4;
  float4 p0 = *reinterpret_cast<const float4*>(pre_bias + c0);
  float acc0 = p0.x, acc1 = p0.y, acc2 = p0.z, acc3 = p0.w;
  for (int j = 0; j < K; ++j) {
    float v = sval[j];
    uint2 wv = *reinterpret_cast<const uint2*>(WdTh + (size_t)sidx[j] * D + c0);
    acc0 = fmaf(v, bf2f((unsigned short)(wv.x & 0xffff)), acc0);
    acc1 = fmaf(v, bf2f((unsigned short)(wv.x >> 16)),    acc1);
    acc2 = fmaf(v, bf2f((unsigned short)(wv.y & 0xffff)), acc2);
    acc3 = fmaf(v, bf2f((unsigned short)(wv.y >> 16)),    acc3);
  }
  float mean = stats[2 * b], sd = stats[2 * b + 1];
  float4 o = make_float4(acc0 * sd + mean, acc1 * sd + mean,
                         acc2 * sd + mean, acc3 * sd + mean);
  *reinterpret_cast<float4*>(recons + (size_t)b * D + c0) = o;
}

// fallback (strided gather from W_dec [D,S])
__global__ __launch_bounds__(256) void decode_fb(
    const float* __restrict__ Wd, const float* __restrict__ pre_bias,
    const float* __restrict__ stats, const int* __restrict__ kp,
    const int* __restrict__ out_idx, const float* __restrict__ out_val,
    float* __restrict__ recons, int D, int S) {
  const int b = blockIdx.x, tid = threadIdx.x;
  __shared__ int sidx[192];
  __shared__ float sval[192];
  int K = kp[0]; if (K > 192) K = 192;
  if (tid < K) { sidx[tid] = out_idx[(size_t)b * 256 + tid]; sval[tid] = out_val[(size_t)b * 256 + tid]; }
  __syncthreads();
  for (int d = tid; d < D; d += 256) {
    float acc = pre_bias[d];
    for (int j = 0; j < K; ++j)
      acc = fmaf(sval[j], Wd[(size_t)d * S + sidx[j]], acc);
    recons[(size_t)b * D + d] = acc * stats[2 * b + 1] + stats[2 * b];
  }
}

extern "C" void kernel_launch(void* const* d_in, const int* in_sizes, int n_in,
                              void* d_out, int out_size, void* d_ws, size_t ws_size,
                              hipStream_t stream) {
  const float* x        = (const float*)d_in[0];
  const float* W_enc    = (const float*)d_in[1];
  const float* W_dec    = (const float*)d_in[2];
  const float* pre_bias = (const float*)d_in[3];
  const float* sae_bias = (const float*)d_in[4];
  const int*   kp       = (const int*)d_in[5];
  const int D = in_sizes[3];
  const int S = in_sizes[4];
  const int B = in_sizes[0] / D;

  float* out_pre = (float*)d_out;
  float* out_lat = out_pre + (size_t)B * S;
  float* out_rec = out_lat + (size_t)B * S;

  char* ws = (char*)d_ws;
  size_t off = 0;
  float* a = (float*)(ws + off);        off += (size_t)B * D * 4;
  float* stats = (float*)(ws + off);    off += (size_t)B * 2 * 4;
  int* cand = (int*)(ws + off);         off += (size_t)B * CAP * 4;
  float* candv = (float*)(ws + off);    off += (size_t)B * CAP * 4;
  int* candcnt = (int*)(ws + off);      off += (size_t)B * 4;
  int* oidx = (int*)(ws + off);         off += (size_t)B * 256 * 4;
  float* oval = (float*)(ws + off);     off += (size_t)B * 256 * 4;
  off = (off + 255) & ~(size_t)255;
  unsigned short* A2 = (unsigned short*)(ws + off);
  size_t offW2 = off + (size_t)B * D * 2;
  unsigned short* W2 = (unsigned short*)(ws + offW2);
  size_t offWdT = offW2 + (size_t)S * D * 2;
  unsigned short* WdTh = (unsigned short*)(ws + offWdT);
  size_t offEnd = offWdT + (size_t)S * D * 2;
  bool useBf16 = (D == 2048) && (B % 128 == 0) && (S % 128 == 0) &&
                 (S % 32 == 0) && (D % 32 == 0) && (ws_size >= offEnd);

  // zero latents up-front (DMA fill) so topk_select is a pure-read kernel
  hipMemsetAsync(out_lat, 0, (size_t)B * S * 4, stream);

  if (useBf16) {
    ln_kernel<<<B, 256, 0, stream>>>(x, pre_bias, a, A2, stats, D);
    cvt_w_kernel<<<S, 256, 0, stream>>>(W_enc, W2, D);
    enc_gemm_bf16<<<dim3(S / 128, B / 128), 512, 0, stream>>>(A2, W2, sae_bias, out_pre, B, S);
    transpose_cvt<<<dim3(S / 32, D / 32), 256, 0, stream>>>(W_dec, WdTh, D, S);
    topk_select<<<B, 256, 0, stream>>>(out_pre, kp, cand, candv, candcnt, S);
    topk_refine<<<B, 256, 0, stream>>>(a, W_enc, sae_bias, kp, cand, candv, candcnt,
                                       out_lat, oidx, oval, D, S);
    decode_bf16<<<B, 512, 0, stream>>>(WdTh, pre_bias, stats, kp, oidx, oval, out_rec, D);
  } else {
    ln_kernel<<<B, 256, 0, stream>>>(x, pre_bias, a, nullptr, stats, D);
    enc_gemm_f32<<<dim3(S / BN, B / BM), 256, 0, stream>>>(a, W_enc, sae_bias, out_pre, B, S, D);
    topk_select<<<B, 256, 0, stream>>>(out_pre, kp, cand, candv, candcnt, S);
    topk_refine<<<B, 256, 0, stream>>>(a, W_enc, sae_bias, kp, cand, candv, candcnt,
                                       out_lat, oidx, oval, D, S);
    decode_fb<<<B, 256, 0, stream>>>(W_dec, pre_bias, stats, kp, oidx, oval, out_rec, D, S);
  }
}